// Round 1
// 509.757 us; speedup vs baseline: 1.1296x; 1.1296x over previous
//
#include <hip/hip_runtime.h>
#include <stdint.h>

#define Bsz 4
#define Nn 4096
#define Dd 512

typedef unsigned short u16;
typedef __attribute__((ext_vector_type(8))) _Float16 f16x8;
typedef __attribute__((ext_vector_type(4))) float f32x4;
typedef __attribute__((address_space(3))) uint32_t lds_as;
typedef __attribute__((address_space(1))) const uint32_t gbl_as;

__device__ __forceinline__ u16 f16_of(float v) {
  _Float16 h = (_Float16)v;           // v_cvt_f16_f32, RN
  return __builtin_bit_cast(u16, h);
}
__device__ __forceinline__ float f_of_f16(u16 u) {
  return (float)__builtin_bit_cast(_Float16, u);   // v_cvt_f32_f16
}

// ---------------- K1: normalize rows -> fp16, store rinv ----------------
__global__ __launch_bounds__(128) void prep_kernel(const float* __restrict__ x,
                                                   float* __restrict__ rinv,
                                                   u16* __restrict__ xh) {
  int row = blockIdx.x;   // B*N rows
  int t = threadIdx.x;    // 128 threads, one float4 each
  const float4* xr = (const float4*)(x + (size_t)row * Dd);
  float4 v = xr[t];
  float s = v.x * v.x + v.y * v.y + v.z * v.z + v.w * v.w;
  for (int o = 32; o > 0; o >>= 1) s += __shfl_down(s, o, 64);
  __shared__ float ls[2];
  if ((t & 63) == 0) ls[t >> 6] = s;
  __syncthreads();
  float ri = 1.0f / fmaxf(sqrtf(ls[0] + ls[1]), 1e-12f);
  if (t == 0) rinv[row] = ri;
  u16 h0 = f16_of(v.x * ri), h1 = f16_of(v.y * ri);
  u16 h2 = f16_of(v.z * ri), h3 = f16_of(v.w * ri);
  uint2 hp;
  hp.x = (uint32_t)h0 | ((uint32_t)h1 << 16);
  hp.y = (uint32_t)h2 | ((uint32_t)h3 << 16);
  *(uint2*)(xh + (size_t)row * Dd + t * 4) = hp;
}

// ---------------- K2: single-pass fp16 symmetric MFMA GEMM, BK=64 ----------------
// LDS: 2 x [128][64] fp16 tiles (A, B), 32 KB, no padding (global_load_lds linear dest).
// XOR slot swizzle: logical 16B k-slot s of row r lives at physical slot s ^ (r&7),
// applied on the GLOBAL source address so ds_read_b128 fragment reads are
// conflict-free (per 16-lane phase: 8 distinct slots x 2 rows = 2-way = free).
__global__ __launch_bounds__(256) void gemm_sym(const u16* __restrict__ xh,
                                                u16* __restrict__ simb) {
  __shared__ __align__(16) u16 lds[2 * 128 * 64];   // 32 KB
  int b = blockIdx.y;
  int p0 = blockIdx.x;
  int p = (p0 & 7) * 66 + (p0 >> 3);   // bijective XCD swizzle (528 = 8*66)
  const int T = Nn / 128;
  int ti = 0;
  while (p >= T - ti) { p -= T - ti; ti++; }
  int tj = ti + p;
  int ri0 = ti * 128, rj0 = tj * 128;
  int tid = threadIdx.x, wid = tid >> 6, lane = tid & 63;
  int wr = (wid >> 1) * 64, wc = (wid & 1) * 64;   // wave's 64x64 quadrant
  int frow = lane & 15, kg = lane >> 4;

  // staging role: tile = wid>>1 (0=A rows@ri0, 1=B rows@rj0), half = wid&1
  int tile = wid >> 1, half = wid & 1;
  int rbase = tile ? rj0 : ri0;
  // lane stages 16B of row (rbase + half*64 + i*8 + lane>>3), k-seg (lane&7)^(lane>>3)
  const u16* sb = xh + ((size_t)b * Nn + rbase + half * 64 + (lane >> 3)) * Dd
                     + (((lane & 7) ^ (lane >> 3)) * 8);
  u16* tb = &lds[tile * 8192 + half * 4096];   // wave-uniform LDS dest base; HW adds lane*16B

  f32x4 acc[4][4];
#pragma unroll
  for (int mt = 0; mt < 4; mt++)
#pragma unroll
    for (int nt = 0; nt < 4; nt++) acc[mt][nt] = (f32x4){0.f, 0.f, 0.f, 0.f};

  for (int k0 = 0; k0 < Dd; k0 += 64) {
    __syncthreads();
#pragma unroll
    for (int i = 0; i < 8; i++) {
      __builtin_amdgcn_global_load_lds((gbl_as*)(sb + (size_t)i * 8 * Dd + k0),
                                       (lds_as*)(tb + i * 512), 16, 0, 0);
    }
    __syncthreads();   // drains vmcnt -> staging visible
#pragma unroll
    for (int kk = 0; kk < 2; kk++) {
      f16x8 bfr[4];
#pragma unroll
      for (int nt = 0; nt < 4; nt++) {
        int rB = wc + nt * 16 + frow;
        int ps = (kk * 4 + kg) ^ (rB & 7);
        bfr[nt] = *(const f16x8*)&lds[8192 + rB * 64 + ps * 8];
      }
#pragma unroll
      for (int mt = 0; mt < 4; mt++) {
        int rA = wr + mt * 16 + frow;
        int ps = (kk * 4 + kg) ^ (rA & 7);
        f16x8 af = *(const f16x8*)&lds[rA * 64 + ps * 8];
#pragma unroll
        for (int nt = 0; nt < 4; nt++)
          acc[mt][nt] = __builtin_amdgcn_mfma_f32_16x16x32_f16(af, bfr[nt], acc[mt][nt], 0, 0, 0);
      }
    }
  }

  // epilogue: C/D layout col=lane&15, row=(lane>>4)*4+reg; write fp16 sim
  u16* ob = simb + (size_t)b * Nn * Nn;
#pragma unroll
  for (int mt = 0; mt < 4; mt++) {
    int rowg0 = ri0 + wr + mt * 16 + (lane >> 4) * 4;
#pragma unroll
    for (int nt = 0; nt < 4; nt++) {
      int colg = rj0 + wc + nt * 16 + frow;
      u16 u0 = f16_of(acc[mt][nt].x);
      u16 u1 = f16_of(acc[mt][nt].y);
      u16 u2 = f16_of(acc[mt][nt].z);
      u16 u3 = f16_of(acc[mt][nt].w);
      ob[(size_t)(rowg0 + 0) * Nn + colg] = u0;
      ob[(size_t)(rowg0 + 1) * Nn + colg] = u1;
      ob[(size_t)(rowg0 + 2) * Nn + colg] = u2;
      ob[(size_t)(rowg0 + 3) * Nn + colg] = u3;
      if (ti != tj) {
        uint2 m;
        m.x = (uint32_t)u0 | ((uint32_t)u1 << 16);
        m.y = (uint32_t)u2 | ((uint32_t)u3 << 16);
        *(uint2*)&ob[(size_t)colg * Nn + rowg0] = m;   // bitwise-identical mirror
      }
    }
  }
}

// ---------------- K3: compact-then-rank select on fp16 sims + fp32 band refinement ----------------
__global__ __launch_bounds__(256) void select_kernel(const u16* __restrict__ simb,
                                                     const float* __restrict__ x,
                                                     const float* __restrict__ rinv,
                                                     uint32_t* __restrict__ bm) {
  int row = blockIdx.x;   // global row in [0, B*N)
  int t = threadIdx.x;    // 256
  const uint4* srow = (const uint4*)(simb + (size_t)row * Nn);
  float val[16];          // val[q*8+e] = element q*2048 + t*8 + e
#pragma unroll
  for (int q = 0; q < 2; q++) {
    uint4 u = srow[t + q * 256];
    val[q * 8 + 0] = f_of_f16((u16)(u.x & 0xFFFFu));
    val[q * 8 + 1] = f_of_f16((u16)(u.x >> 16));
    val[q * 8 + 2] = f_of_f16((u16)(u.y & 0xFFFFu));
    val[q * 8 + 3] = f_of_f16((u16)(u.y >> 16));
    val[q * 8 + 4] = f_of_f16((u16)(u.z & 0xFFFFu));
    val[q * 8 + 5] = f_of_f16((u16)(u.z >> 16));
    val[q * 8 + 6] = f_of_f16((u16)(u.w & 0xFFFFu));
    val[q * 8 + 7] = f_of_f16((u16)(u.w >> 16));
  }
  __shared__ float lv[2048];
  __shared__ int li[2048];
  __shared__ int red[4];
  __shared__ uint32_t lmask[128];
  __shared__ int bandIdx[128];
  __shared__ float bandV[128];
  __shared__ int listCnt, bandCnt;
  __shared__ float sS;
  if (t < 128) lmask[t] = 0;
  if (t == 0) { listCnt = 0; bandCnt = 0; }

  // --- probe a compaction threshold (descending; break at >=36 candidates) ---
  const float probes[8] = {0.08f, 0.05f, 0.02f, -0.02f, -0.1f, -0.3f, -0.7f, -2.0f};
  float theta = -2.0f;
  for (int pi = 0; pi < 8; pi++) {
    theta = probes[pi];
    int c = 0;
#pragma unroll
    for (int i = 0; i < 16; i++) c += (val[i] > theta) ? 1 : 0;
    for (int o = 32; o > 0; o >>= 1) c += __shfl_down(c, o, 64);
    __syncthreads();
    if ((t & 63) == 0) red[t >> 6] = c;
    __syncthreads();
    int total = red[0] + red[1] + red[2] + red[3];
    if (total >= 36) break;
  }

  // --- compact candidates (value, index) to LDS ---
#pragma unroll
  for (int i = 0; i < 16; i++) {
    if (val[i] > theta) {
      int s = atomicAdd(&listCnt, 1);
      if (s < 2048) { lv[s] = val[i]; li[s] = (i >> 3) * 2048 + t * 8 + (i & 7); }
    }
  }
  __syncthreads();
  int L = listCnt; if (L > 2048) L = 2048;

  // --- exact rank of each candidate; entry with rank 31 is the 32nd largest ---
  for (int e = t; e < L; e += 256) {
    float ve = lv[e]; int ie = li[e];
    int rank = 0;
    for (int q = 0; q < L; q++) {
      float vq = lv[q];
      int iq = li[q];
      rank += ((vq > ve) || (vq == ve && iq < ie)) ? 1 : 0;
    }
    if (rank == 31) sS = ve;
  }
  __syncthreads();
  float S = sS;
  // fp16 path: storage half-ulp |S|*2^-12 + MFMA-input err (~1e-4 worst); eb >= 2*e_max
  float eb = fmaxf(3e-4f, fabsf(S) * 1e-3f);
  float hiT = S + eb, loT = S - eb;

  // --- classify ALL elements; band -> exact fp32 refinement ---
  int aCnt = 0;
  uint32_t patLo = 0, patHi = 0;
#pragma unroll
  for (int i = 0; i < 16; i++) {
    float v = val[i];
    if (v > hiT) {
      if (i < 8) patLo |= 1u << i; else patHi |= 1u << (i - 8);
      aCnt++;
    } else if (v >= loT) {
      int s = atomicAdd(&bandCnt, 1);
      if (s < 128) bandIdx[s] = (i >> 3) * 2048 + t * 8 + (i & 7);
    }
  }
  for (int o = 32; o > 0; o >>= 1) aCnt += __shfl_down(aCnt, o, 64);
  __syncthreads();
  if ((t & 63) == 0) red[t >> 6] = aCnt;
  if (patLo) atomicOr(&lmask[t >> 2], patLo << ((t & 3) * 8));
  if (patHi) atomicOr(&lmask[64 + (t >> 2)], patHi << ((t & 3) * 8));
  __syncthreads();

  int A = red[0] + red[1] + red[2] + red[3];   // robustly above
  int BC = bandCnt; if (BC > 128) BC = 128;
  int need = 32 - A;                            // 1 <= need <= BC
  bool heavy = (BC > need);
  if (heavy) {
    // recompute band sims with the round-1 fp32 chain
    const float* xn = x + (size_t)row * Dd;
    float ra = rinv[row];
    int bb = row >> 12;
    const float* xbb = x + ((size_t)bb << 12) * Dd;
    for (int s = t; s < BC; s += 256) {
      int m = bandIdx[s];
      const float* xm = xbb + (size_t)m * Dd;
      float dot = 0.f;
      for (int k = 0; k < Dd; k += 4) {
        float4 a4 = *(const float4*)(xn + k);
        float4 b4 = *(const float4*)(xm + k);
        dot = fmaf(a4.x, b4.x, dot);
        dot = fmaf(a4.y, b4.y, dot);
        dot = fmaf(a4.z, b4.z, dot);
        dot = fmaf(a4.w, b4.w, dot);
      }
      bandV[s] = (dot * ra) * rinv[((size_t)bb << 12) + m];
    }
  }
  __syncthreads();
  if (t == 0) {
    if (!heavy) {
      for (int s = 0; s < BC; s++) {
        int gi = bandIdx[s];
        lmask[gi >> 5] |= 1u << (gi & 31);
      }
    } else {
      for (int s = 0; s < need; s++) {   // top-need by (value desc, index asc)
        float bv = -1e30f; int bidx = 0x7FFFFFFF, bs = -1;
        for (int q = 0; q < BC; q++) {
          int gi = bandIdx[q];
          if (gi < 0) continue;
          float v = bandV[q];
          if (v > bv || (v == bv && gi < bidx)) { bv = v; bidx = gi; bs = q; }
        }
        if (bs < 0) break;
        bandIdx[bs] = -1;
        lmask[bidx >> 5] |= 1u << (bidx & 31);
      }
    }
  }
  __syncthreads();
  if (t < 128) bm[(size_t)row * 128 + t] = lmask[t];
}

// ---------------- K4: masked symmetrize, fp16 sim -> fp32 out ----------------
__global__ __launch_bounds__(256) void finalize_kernel(const u16* __restrict__ simb,
                                                       float* __restrict__ out,
                                                       const uint32_t* __restrict__ bm) {
  __shared__ float Tt[64][65];
  __shared__ uint32_t kA[64][2], kB[64][2];
  int b = blockIdx.y;
  int p = blockIdx.x;             // 0..2079 (T=64)
  const int T = Nn / 64;
  int ti = 0;
  while (p >= T - ti) { p -= T - ti; ti++; }
  int tj = ti + p;
  int ri0 = ti * 64, rj0 = tj * 64;
  int t = threadIdx.x;
  const uint32_t* bmb = bm + (size_t)b * Nn * 128;
  if (t < 128) {
    kA[t >> 1][t & 1] = bmb[(size_t)(ri0 + (t >> 1)) * 128 + (rj0 >> 5) + (t & 1)];
  } else {
    int tt = t - 128;
    kB[tt >> 1][tt & 1] = bmb[(size_t)(rj0 + (tt >> 1)) * 128 + (ri0 >> 5) + (tt & 1)];
  }
  __syncthreads();
  const u16* sbase = simb + (size_t)b * Nn * Nn;
  float* ob = out + (size_t)b * Nn * Nn;
#pragma unroll
  for (int it = 0; it < 2; it++) {
    int pq = it * 256 + t;          // 512 ushort8-units in the 64x64 tile
    int nl = pq >> 3;
    int ml = (pq & 7) * 8;
    uint4 u = *(const uint4*)(sbase + (size_t)(ri0 + nl) * Nn + rj0 + ml);
    float s0 = f_of_f16((u16)(u.x & 0xFFFFu)), s1 = f_of_f16((u16)(u.x >> 16));
    float s2 = f_of_f16((u16)(u.y & 0xFFFFu)), s3 = f_of_f16((u16)(u.y >> 16));
    float s4 = f_of_f16((u16)(u.z & 0xFFFFu)), s5 = f_of_f16((u16)(u.z >> 16));
    float s6 = f_of_f16((u16)(u.w & 0xFFFFu)), s7 = f_of_f16((u16)(u.w >> 16));
    uint32_t ka = kA[nl][ml >> 5] >> (ml & 31);   // 8 bits, same word (ml%32 in {0,8,16,24})
    uint32_t nw = nl >> 5, nb = nl & 31;
    float4 v0, v1;
    v0.x = 0.5f * s0 * (float)(((ka >> 0) & 1u) + ((kB[ml + 0][nw] >> nb) & 1u));
    v0.y = 0.5f * s1 * (float)(((ka >> 1) & 1u) + ((kB[ml + 1][nw] >> nb) & 1u));
    v0.z = 0.5f * s2 * (float)(((ka >> 2) & 1u) + ((kB[ml + 2][nw] >> nb) & 1u));
    v0.w = 0.5f * s3 * (float)(((ka >> 3) & 1u) + ((kB[ml + 3][nw] >> nb) & 1u));
    v1.x = 0.5f * s4 * (float)(((ka >> 4) & 1u) + ((kB[ml + 4][nw] >> nb) & 1u));
    v1.y = 0.5f * s5 * (float)(((ka >> 5) & 1u) + ((kB[ml + 5][nw] >> nb) & 1u));
    v1.z = 0.5f * s6 * (float)(((ka >> 6) & 1u) + ((kB[ml + 6][nw] >> nb) & 1u));
    v1.w = 0.5f * s7 * (float)(((ka >> 7) & 1u) + ((kB[ml + 7][nw] >> nb) & 1u));
    size_t addr = (size_t)(ri0 + nl) * Nn + rj0 + ml;
    *(float4*)(ob + addr) = v0;
    *(float4*)(ob + addr + 4) = v1;
    Tt[ml + 0][nl] = v0.x; Tt[ml + 1][nl] = v0.y; Tt[ml + 2][nl] = v0.z; Tt[ml + 3][nl] = v0.w;
    Tt[ml + 4][nl] = v1.x; Tt[ml + 5][nl] = v1.y; Tt[ml + 6][nl] = v1.z; Tt[ml + 7][nl] = v1.w;
  }
  if (ti != tj) {
    __syncthreads();
#pragma unroll
    for (int it = 0; it < 4; it++) {
      int pq = it * 256 + t;
      int nl = pq >> 4;
      int ml = (pq & 15) << 2;
      float4 v;
      v.x = Tt[nl][ml + 0]; v.y = Tt[nl][ml + 1];
      v.z = Tt[nl][ml + 2]; v.w = Tt[nl][ml + 3];
      *(float4*)(ob + (size_t)(rj0 + nl) * Nn + ri0 + ml) = v;
    }
  }
}

extern "C" void kernel_launch(void* const* d_in, const int* in_sizes, int n_in,
                              void* d_out, int out_size, void* d_ws, size_t ws_size,
                              hipStream_t stream) {
  const float* x = (const float*)d_in[0];
  float* out = (float*)d_out;
  // ws layout (16B-aligned): rinv 64KB | bm 8MB | xh 16MB | simb 128MB
  float* rinv = (float*)d_ws;
  uint32_t* bm = (uint32_t*)((char*)d_ws + (1u << 16));
  u16* xh = (u16*)((char*)d_ws + (1u << 16) + (8u << 20));
  u16* simb = xh + (size_t)Bsz * Nn * Dd;

  prep_kernel<<<Bsz * Nn, 128, 0, stream>>>(x, rinv, xh);
  dim3 g2(528, Bsz);
  gemm_sym<<<g2, 256, 0, stream>>>(xh, simb);
  select_kernel<<<Bsz * Nn, 256, 0, stream>>>(simb, x, rinv, bm);
  dim3 g4(2080, Bsz);
  finalize_kernel<<<g4, 256, 0, stream>>>(simb, out, bm);
}

// Round 2
// 509.503 us; speedup vs baseline: 1.1301x; 1.0005x over previous
//
#include <hip/hip_runtime.h>
#include <stdint.h>

#define Bsz 4
#define Nn 4096
#define Dd 512

typedef unsigned short u16;
typedef __attribute__((ext_vector_type(8))) _Float16 f16x8;
typedef __attribute__((ext_vector_type(4))) float f32x4;
typedef __attribute__((address_space(3))) uint32_t lds_as;
typedef __attribute__((address_space(1))) const uint32_t gbl_as;

__device__ __forceinline__ u16 f16_of(float v) {
  _Float16 h = (_Float16)v;           // v_cvt_f16_f32, RN
  return __builtin_bit_cast(u16, h);
}
__device__ __forceinline__ float f_of_f16(u16 u) {
  return (float)__builtin_bit_cast(_Float16, u);   // v_cvt_f32_f16
}

// ---------------- K1: normalize rows -> fp16, store rinv ----------------
__global__ __launch_bounds__(128) void prep_kernel(const float* __restrict__ x,
                                                   float* __restrict__ rinv,
                                                   u16* __restrict__ xh) {
  int row = blockIdx.x;   // B*N rows
  int t = threadIdx.x;    // 128 threads, one float4 each
  const float4* xr = (const float4*)(x + (size_t)row * Dd);
  float4 v = xr[t];
  float s = v.x * v.x + v.y * v.y + v.z * v.z + v.w * v.w;
  for (int o = 32; o > 0; o >>= 1) s += __shfl_down(s, o, 64);
  __shared__ float ls[2];
  if ((t & 63) == 0) ls[t >> 6] = s;
  __syncthreads();
  float ri = 1.0f / fmaxf(sqrtf(ls[0] + ls[1]), 1e-12f);
  if (t == 0) rinv[row] = ri;
  u16 h0 = f16_of(v.x * ri), h1 = f16_of(v.y * ri);
  u16 h2 = f16_of(v.z * ri), h3 = f16_of(v.w * ri);
  uint2 hp;
  hp.x = (uint32_t)h0 | ((uint32_t)h1 << 16);
  hp.y = (uint32_t)h2 | ((uint32_t)h3 << 16);
  *(uint2*)(xh + (size_t)row * Dd + t * 4) = hp;
}

// ---------------- K2: single-pass fp16 symmetric MFMA GEMM, BK=64 ----------------
// LDS: 2 x [128][64] fp16 tiles (A, B), 32 KB, no padding (global_load_lds linear dest).
// XOR slot swizzle: logical 16B k-slot s of row r lives at physical slot s ^ (r&7),
// applied on the GLOBAL source address so ds_read_b128 fragment reads are
// conflict-free.
// Epilogue: direct tile stored per-lane (32B segments); mirror tile bounced through
// LDS transposed (ds_write_b64, XOR swizzle) and streamed out as coalesced dwordx4.
__global__ __launch_bounds__(256) void gemm_sym(const u16* __restrict__ xh,
                                                u16* __restrict__ simb) {
  __shared__ __align__(16) u16 lds[2 * 128 * 64];   // 32 KB; reused as ldsT[128][128] in epilogue
  int b = blockIdx.y;
  int p0 = blockIdx.x;
  int p = (p0 & 7) * 66 + (p0 >> 3);   // bijective XCD swizzle (528 = 8*66)
  const int T = Nn / 128;
  int ti = 0;
  while (p >= T - ti) { p -= T - ti; ti++; }
  int tj = ti + p;
  int ri0 = ti * 128, rj0 = tj * 128;
  int tid = threadIdx.x, wid = tid >> 6, lane = tid & 63;
  int wr = (wid >> 1) * 64, wc = (wid & 1) * 64;   // wave's 64x64 quadrant
  int frow = lane & 15, kg = lane >> 4;

  // staging role: tile = wid>>1 (0=A rows@ri0, 1=B rows@rj0), half = wid&1
  int tile = wid >> 1, half = wid & 1;
  int rbase = tile ? rj0 : ri0;
  // lane stages 16B of row (rbase + half*64 + i*8 + lane>>3), k-seg (lane&7)^(lane>>3)
  const u16* sb = xh + ((size_t)b * Nn + rbase + half * 64 + (lane >> 3)) * Dd
                     + (((lane & 7) ^ (lane >> 3)) * 8);
  u16* tb = &lds[tile * 8192 + half * 4096];   // wave-uniform LDS dest base; HW adds lane*16B

  f32x4 acc[4][4];
#pragma unroll
  for (int mt = 0; mt < 4; mt++)
#pragma unroll
    for (int nt = 0; nt < 4; nt++) acc[mt][nt] = (f32x4){0.f, 0.f, 0.f, 0.f};

  for (int k0 = 0; k0 < Dd; k0 += 64) {
    __syncthreads();
#pragma unroll
    for (int i = 0; i < 8; i++) {
      __builtin_amdgcn_global_load_lds((gbl_as*)(sb + (size_t)i * 8 * Dd + k0),
                                       (lds_as*)(tb + i * 512), 16, 0, 0);
    }
    __syncthreads();   // drains vmcnt -> staging visible
#pragma unroll
    for (int kk = 0; kk < 2; kk++) {
      f16x8 bfr[4];
#pragma unroll
      for (int nt = 0; nt < 4; nt++) {
        int rB = wc + nt * 16 + frow;
        int ps = (kk * 4 + kg) ^ (rB & 7);
        bfr[nt] = *(const f16x8*)&lds[8192 + rB * 64 + ps * 8];
      }
#pragma unroll
      for (int mt = 0; mt < 4; mt++) {
        int rA = wr + mt * 16 + frow;
        int ps = (kk * 4 + kg) ^ (rA & 7);
        f16x8 af = *(const f16x8*)&lds[rA * 64 + ps * 8];
#pragma unroll
        for (int nt = 0; nt < 4; nt++)
          acc[mt][nt] = __builtin_amdgcn_mfma_f32_16x16x32_f16(af, bfr[nt], acc[mt][nt], 0, 0, 0);
      }
    }
  }

  // ---- epilogue ----
  // C/D layout: col = lane&15 (frow), rows = (lane>>4)*4 + reg.
  __syncthreads();   // all waves done reading staging LDS before ldsT overwrite
  u16* ob = simb + (size_t)b * Nn * Nn;
  bool offdiag = (ti != tj);
#pragma unroll
  for (int mt = 0; mt < 4; mt++) {
    int R0 = wr + mt * 16 + (lane >> 4) * 4;   // local row base (mult of 4)
    int rowg0 = ri0 + R0;
#pragma unroll
    for (int nt = 0; nt < 4; nt++) {
      int C = wc + nt * 16 + frow;             // local col
      int colg = rj0 + C;
      u16 u0 = f16_of(acc[mt][nt].x);
      u16 u1 = f16_of(acc[mt][nt].y);
      u16 u2 = f16_of(acc[mt][nt].z);
      u16 u3 = f16_of(acc[mt][nt].w);
      ob[(size_t)(rowg0 + 0) * Nn + colg] = u0;
      ob[(size_t)(rowg0 + 1) * Nn + colg] = u1;
      ob[(size_t)(rowg0 + 2) * Nn + colg] = u2;
      ob[(size_t)(rowg0 + 3) * Nn + colg] = u3;
      if (offdiag) {
        // transposed LDS image: logical (C, R) at u16-index C*128 + (R ^ ((C&15)<<3))
        uint2 m;
        m.x = (uint32_t)u0 | ((uint32_t)u1 << 16);
        m.y = (uint32_t)u2 | ((uint32_t)u3 << 16);
        *(uint2*)&lds[C * 128 + (R0 ^ ((C & 15) << 3))] = m;
      }
    }
  }
  if (offdiag) {
    __syncthreads();
    // stream mirror tile rows out coalesced: mirror row (rj0+C), cols ri0..ri0+127
#pragma unroll
    for (int pass = 0; pass < 8; pass++) {
      int C = pass * 16 + (tid >> 4);
      int k = tid & 15;                        // logical 8-elem chunk (R = 8k..8k+7)
      int kp = k ^ (C & 15);                   // physical chunk after swizzle
      uint4 d = *(const uint4*)&lds[C * 128 + kp * 8];
      *(uint4*)&ob[(size_t)(rj0 + C) * Nn + ri0 + k * 8] = d;
    }
  }
}

// ---------------- K3: compact-then-rank select on fp16 sims + fp32 band refinement ----------------
__global__ __launch_bounds__(256) void select_kernel(const u16* __restrict__ simb,
                                                     const float* __restrict__ x,
                                                     const float* __restrict__ rinv,
                                                     uint32_t* __restrict__ bm) {
  int row = blockIdx.x;   // global row in [0, B*N)
  int t = threadIdx.x;    // 256
  int lane = t & 63;
  const uint4* srow = (const uint4*)(simb + (size_t)row * Nn);
  float val[16];          // val[q*8+e] = element q*2048 + t*8 + e
#pragma unroll
  for (int q = 0; q < 2; q++) {
    uint4 u = srow[t + q * 256];
    val[q * 8 + 0] = f_of_f16((u16)(u.x & 0xFFFFu));
    val[q * 8 + 1] = f_of_f16((u16)(u.x >> 16));
    val[q * 8 + 2] = f_of_f16((u16)(u.y & 0xFFFFu));
    val[q * 8 + 3] = f_of_f16((u16)(u.y >> 16));
    val[q * 8 + 4] = f_of_f16((u16)(u.z & 0xFFFFu));
    val[q * 8 + 5] = f_of_f16((u16)(u.z >> 16));
    val[q * 8 + 6] = f_of_f16((u16)(u.w & 0xFFFFu));
    val[q * 8 + 7] = f_of_f16((u16)(u.w >> 16));
  }
  __shared__ float lv[2048];
  __shared__ int li[2048];
  __shared__ int red[4];
  __shared__ uint32_t lmask[128];
  __shared__ int bandIdx[128];
  __shared__ float bandV[128];
  __shared__ int listCnt, bandCnt;
  __shared__ float sS;
  if (t < 128) lmask[t] = 0;
  if (t == 0) { listCnt = 0; bandCnt = 0; }

  // --- probe a compaction threshold (descending; break at >=36 candidates) ---
  const float probes[8] = {0.08f, 0.05f, 0.02f, -0.02f, -0.1f, -0.3f, -0.7f, -2.0f};
  float theta = -2.0f;
  for (int pi = 0; pi < 8; pi++) {
    theta = probes[pi];
    int c = 0;
#pragma unroll
    for (int i = 0; i < 16; i++) c += (val[i] > theta) ? 1 : 0;
    for (int o = 32; o > 0; o >>= 1) c += __shfl_down(c, o, 64);
    __syncthreads();
    if (lane == 0) red[t >> 6] = c;
    __syncthreads();
    int total = red[0] + red[1] + red[2] + red[3];
    if (total >= 36) break;
  }

  // --- compact candidates (value, index) to LDS; wave-ballot, 1 atomic/wave/slot ---
#pragma unroll
  for (int i = 0; i < 16; i++) {
    bool pred = val[i] > theta;
    unsigned long long m = __ballot(pred);
    int base = 0;
    if (lane == 0) {
      int cnt = __popcll(m);
      base = cnt ? atomicAdd(&listCnt, cnt) : 0;
    }
    base = __shfl(base, 0, 64);
    if (pred) {
      int pos = base + __popcll(m & ((1ull << lane) - 1));
      if (pos < 2048) { lv[pos] = val[i]; li[pos] = (i >> 3) * 2048 + t * 8 + (i & 7); }
    }
  }
  __syncthreads();
  int L = listCnt; if (L > 2048) L = 2048;

  // --- exact rank of each candidate; entry with rank 31 is the 32nd largest ---
  for (int e = t; e < L; e += 256) {
    float ve = lv[e]; int ie = li[e];
    int rank = 0;
    for (int q = 0; q < L; q++) {
      float vq = lv[q];
      int iq = li[q];
      rank += ((vq > ve) || (vq == ve && iq < ie)) ? 1 : 0;
    }
    if (rank == 31) sS = ve;
  }
  __syncthreads();
  float S = sS;
  // fp16 path: storage half-ulp |S|*2^-12 + MFMA-input err (~1e-4 worst); eb >= 2*e_max
  float eb = fmaxf(3e-4f, fabsf(S) * 1e-3f);
  float hiT = S + eb, loT = S - eb;

  // --- classify ALL elements; band -> exact fp32 refinement ---
  int aCnt = 0;
  uint32_t patLo = 0, patHi = 0;
#pragma unroll
  for (int i = 0; i < 16; i++) {
    float v = val[i];
    if (v > hiT) {
      if (i < 8) patLo |= 1u << i; else patHi |= 1u << (i - 8);
      aCnt++;
    } else if (v >= loT) {
      int s = atomicAdd(&bandCnt, 1);
      if (s < 128) bandIdx[s] = (i >> 3) * 2048 + t * 8 + (i & 7);
    }
  }
  for (int o = 32; o > 0; o >>= 1) aCnt += __shfl_down(aCnt, o, 64);
  __syncthreads();
  if (lane == 0) red[t >> 6] = aCnt;
  if (patLo) atomicOr(&lmask[t >> 2], patLo << ((t & 3) * 8));
  if (patHi) atomicOr(&lmask[64 + (t >> 2)], patHi << ((t & 3) * 8));
  __syncthreads();

  int A = red[0] + red[1] + red[2] + red[3];   // robustly above
  int BC = bandCnt; if (BC > 128) BC = 128;
  int need = 32 - A;                            // 1 <= need <= BC
  bool heavy = (BC > need);
  if (heavy) {
    // recompute band sims with the round-1 fp32 chain
    const float* xn = x + (size_t)row * Dd;
    float ra = rinv[row];
    int bb = row >> 12;
    const float* xbb = x + ((size_t)bb << 12) * Dd;
    for (int s = t; s < BC; s += 256) {
      int m = bandIdx[s];
      const float* xm = xbb + (size_t)m * Dd;
      float dot = 0.f;
      for (int k = 0; k < Dd; k += 4) {
        float4 a4 = *(const float4*)(xn + k);
        float4 b4 = *(const float4*)(xm + k);
        dot = fmaf(a4.x, b4.x, dot);
        dot = fmaf(a4.y, b4.y, dot);
        dot = fmaf(a4.z, b4.z, dot);
        dot = fmaf(a4.w, b4.w, dot);
      }
      bandV[s] = (dot * ra) * rinv[((size_t)bb << 12) + m];
    }
  }
  __syncthreads();
  if (t == 0) {
    if (!heavy) {
      for (int s = 0; s < BC; s++) {
        int gi = bandIdx[s];
        lmask[gi >> 5] |= 1u << (gi & 31);
      }
    } else {
      for (int s = 0; s < need; s++) {   // top-need by (value desc, index asc)
        float bv = -1e30f; int bidx = 0x7FFFFFFF, bs = -1;
        for (int q = 0; q < BC; q++) {
          int gi = bandIdx[q];
          if (gi < 0) continue;
          float v = bandV[q];
          if (v > bv || (v == bv && gi < bidx)) { bv = v; bidx = gi; bs = q; }
        }
        if (bs < 0) break;
        bandIdx[bs] = -1;
        lmask[bidx >> 5] |= 1u << (bidx & 31);
      }
    }
  }
  __syncthreads();
  if (t < 128) bm[(size_t)row * 128 + t] = lmask[t];
}

// ---------------- K4: masked symmetrize, fp16 sim -> fp32 out; exact 1.0 diagonal ----------------
__global__ __launch_bounds__(256) void finalize_kernel(const u16* __restrict__ simb,
                                                       float* __restrict__ out,
                                                       const uint32_t* __restrict__ bm) {
  __shared__ float Tt[64][65];
  __shared__ uint32_t kA[64][2], kB[64][2];
  int b = blockIdx.y;
  int p = blockIdx.x;             // 0..2079 (T=64)
  const int T = Nn / 64;
  int ti = 0;
  while (p >= T - ti) { p -= T - ti; ti++; }
  int tj = ti + p;
  int ri0 = ti * 64, rj0 = tj * 64;
  int t = threadIdx.x;
  const uint32_t* bmb = bm + (size_t)b * Nn * 128;
  if (t < 128) {
    kA[t >> 1][t & 1] = bmb[(size_t)(ri0 + (t >> 1)) * 128 + (rj0 >> 5) + (t & 1)];
  } else {
    int tt = t - 128;
    kB[tt >> 1][tt & 1] = bmb[(size_t)(rj0 + (tt >> 1)) * 128 + (ri0 >> 5) + (tt & 1)];
  }
  __syncthreads();
  const u16* sbase = simb + (size_t)b * Nn * Nn;
  float* ob = out + (size_t)b * Nn * Nn;
  bool diag = (ti == tj);
#pragma unroll
  for (int it = 0; it < 2; it++) {
    int pq = it * 256 + t;          // 512 ushort8-units in the 64x64 tile
    int nl = pq >> 3;
    int ml = (pq & 7) * 8;
    uint4 u = *(const uint4*)(sbase + (size_t)(ri0 + nl) * Nn + rj0 + ml);
    float s0 = f_of_f16((u16)(u.x & 0xFFFFu)), s1 = f_of_f16((u16)(u.x >> 16));
    float s2 = f_of_f16((u16)(u.y & 0xFFFFu)), s3 = f_of_f16((u16)(u.y >> 16));
    float s4 = f_of_f16((u16)(u.z & 0xFFFFu)), s5 = f_of_f16((u16)(u.z >> 16));
    float s6 = f_of_f16((u16)(u.w & 0xFFFFu)), s7 = f_of_f16((u16)(u.w >> 16));
    if (diag) {
      int d = nl - ml;   // element d of this chunk is the exact diagonal (sim(i,i)=1)
      s0 = (d == 0) ? 1.0f : s0;
      s1 = (d == 1) ? 1.0f : s1;
      s2 = (d == 2) ? 1.0f : s2;
      s3 = (d == 3) ? 1.0f : s3;
      s4 = (d == 4) ? 1.0f : s4;
      s5 = (d == 5) ? 1.0f : s5;
      s6 = (d == 6) ? 1.0f : s6;
      s7 = (d == 7) ? 1.0f : s7;
    }
    uint32_t ka = kA[nl][ml >> 5] >> (ml & 31);   // 8 bits, same word (ml%32 in {0,8,16,24})
    uint32_t nw = nl >> 5, nb = nl & 31;
    float4 v0, v1;
    v0.x = 0.5f * s0 * (float)(((ka >> 0) & 1u) + ((kB[ml + 0][nw] >> nb) & 1u));
    v0.y = 0.5f * s1 * (float)(((ka >> 1) & 1u) + ((kB[ml + 1][nw] >> nb) & 1u));
    v0.z = 0.5f * s2 * (float)(((ka >> 2) & 1u) + ((kB[ml + 2][nw] >> nb) & 1u));
    v0.w = 0.5f * s3 * (float)(((ka >> 3) & 1u) + ((kB[ml + 3][nw] >> nb) & 1u));
    v1.x = 0.5f * s4 * (float)(((ka >> 4) & 1u) + ((kB[ml + 4][nw] >> nb) & 1u));
    v1.y = 0.5f * s5 * (float)(((ka >> 5) & 1u) + ((kB[ml + 5][nw] >> nb) & 1u));
    v1.z = 0.5f * s6 * (float)(((ka >> 6) & 1u) + ((kB[ml + 6][nw] >> nb) & 1u));
    v1.w = 0.5f * s7 * (float)(((ka >> 7) & 1u) + ((kB[ml + 7][nw] >> nb) & 1u));
    size_t addr = (size_t)(ri0 + nl) * Nn + rj0 + ml;
    *(float4*)(ob + addr) = v0;
    *(float4*)(ob + addr + 4) = v1;
    Tt[ml + 0][nl] = v0.x; Tt[ml + 1][nl] = v0.y; Tt[ml + 2][nl] = v0.z; Tt[ml + 3][nl] = v0.w;
    Tt[ml + 4][nl] = v1.x; Tt[ml + 5][nl] = v1.y; Tt[ml + 6][nl] = v1.z; Tt[ml + 7][nl] = v1.w;
  }
  if (ti != tj) {
    __syncthreads();
#pragma unroll
    for (int it = 0; it < 4; it++) {
      int pq = it * 256 + t;
      int nl = pq >> 4;
      int ml = (pq & 15) << 2;
      float4 v;
      v.x = Tt[nl][ml + 0]; v.y = Tt[nl][ml + 1];
      v.z = Tt[nl][ml + 2]; v.w = Tt[nl][ml + 3];
      *(float4*)(ob + (size_t)(rj0 + nl) * Nn + ri0 + ml) = v;
    }
  }
}

extern "C" void kernel_launch(void* const* d_in, const int* in_sizes, int n_in,
                              void* d_out, int out_size, void* d_ws, size_t ws_size,
                              hipStream_t stream) {
  const float* x = (const float*)d_in[0];
  float* out = (float*)d_out;
  // ws layout (16B-aligned): rinv 64KB | bm 8MB | xh 16MB | simb 128MB
  float* rinv = (float*)d_ws;
  uint32_t* bm = (uint32_t*)((char*)d_ws + (1u << 16));
  u16* xh = (u16*)((char*)d_ws + (1u << 16) + (8u << 20));
  u16* simb = xh + (size_t)Bsz * Nn * Dd;

  prep_kernel<<<Bsz * Nn, 128, 0, stream>>>(x, rinv, xh);
  dim3 g2(528, Bsz);
  gemm_sym<<<g2, 256, 0, stream>>>(xh, simb);
  select_kernel<<<Bsz * Nn, 256, 0, stream>>>(simb, x, rinv, bm);
  dim3 g4(2080, Bsz);
  finalize_kernel<<<g4, 256, 0, stream>>>(simb, out, bm);
}